// Round 18
// baseline (94.559 us; speedup 1.0000x reference)
//
#include <hip/hip_runtime.h>
#include <hip/hip_bf16.h>

// SimpleGATLayer fused kernel set for MI355X (gfx950).
// B=8, N=2048, F=U=128 (hard-coded from reference setup).
//
//  k_h    : W->LDS transpose + H = X@W via MFMA -> HT(b,u,n) bf16, s, t
//  k_attn : fused masked softmax(leaky(s_i+t_j)) @ H, relu, f32 out.
//           Round 18: MAX-TLP barrier-free. 16-row blocks, 4 waves (one per
//           512-j quarter), grid 1024 = 4 blocks/CU = 16 waves/CU (2x all
//           prior rounds), __launch_bounds__(256,4). Register pipeline:
//           B half-tile double-buffer (bA/bB), A/t depth-2 issued LAST each
//           iteration so no consumption wait drains a younger A group
//           (in-order vmcnt). LDS only for the j-quarter combine.

#define NEG_INF -1.0e9f

typedef __bf16 bf16x8 __attribute__((ext_vector_type(8)));
typedef unsigned short ushort8 __attribute__((ext_vector_type(8)));
typedef float f32x4 __attribute__((ext_vector_type(4)));

__device__ __forceinline__ unsigned short f2b(float x) {
    // f32 -> bf16 round-to-nearest-even
    unsigned u = __builtin_bit_cast(unsigned, x);
    u += 0x7fffu + ((u >> 16) & 1u);
    return (unsigned short)(u >> 16);
}

// ---------------- K1: H = X@W, plus s,t and HT (W transposed in-kernel) ----
// grid = 256 blocks x 256 thr; each wave computes 16 rows x 128 u.
__global__ __launch_bounds__(256) void k_h(const float* __restrict__ X,
                                           const float* __restrict__ W,
                                           const float* __restrict__ a,
                                           unsigned short* __restrict__ HT,
                                           float* __restrict__ sbuf,
                                           float* __restrict__ tbuf) {
    __shared__ unsigned short WT[128 * 136];   // padded stride: bank spread

    const int tid  = threadIdx.x;
    const int w    = tid >> 6;
    const int lane = tid & 63;
    const int r    = lane & 15;     // MFMA row/col index
    const int cg   = lane >> 4;     // k-group 0..3

    // cooperative W transpose: WT[u][f] = bf16(W[f][u])
    for (int i = tid; i < 16384; i += 256) {
        int u = i >> 7, f = i & 127;
        WT[u * 136 + f] = f2b(W[f * 128 + u]);
    }
    __syncthreads();

    const int row0 = blockIdx.x * 64 + w * 16;  // flattened (b*2048+n) row
    const int b    = row0 >> 11;
    const int n0   = row0 & 2047;
    const int arow = row0 + r;

    f32x4 acc[8] = {};

#pragma unroll
    for (int k0 = 0; k0 < 128; k0 += 32) {
        const float* xp = X + (size_t)arow * 128 + k0 + cg * 8;
        ushort8 xa;
#pragma unroll
        for (int j = 0; j < 8; j++) xa[j] = f2b(xp[j]);
        bf16x8 av = __builtin_bit_cast(bf16x8, xa);
#pragma unroll
        for (int ut = 0; ut < 8; ut++) {
            ushort8 wb = *(const ushort8*)(&WT[(ut * 16 + r) * 136 + k0 + cg * 8]);
            acc[ut] = __builtin_amdgcn_mfma_f32_16x16x32_bf16(
                av, __builtin_bit_cast(bf16x8, wb), acc[ut], 0, 0, 0);
        }
    }

    // D layout: lane holds H[row0 + cg*4 + reg][ut*16 + r]
    float sp[4] = {0.f, 0.f, 0.f, 0.f};
    float tp[4] = {0.f, 0.f, 0.f, 0.f};
#pragma unroll
    for (int ut = 0; ut < 8; ut++) {
        int u = ut * 16 + r;
        float as = a[u];
        float ad = a[128 + u];
#pragma unroll
        for (int reg = 0; reg < 4; reg++) {
            float h = acc[ut][reg];
            int nrow = n0 + cg * 4 + reg;
            HT[((size_t)b * 128 + u) * 2048 + nrow] = f2b(h);
            sp[reg] += h * as;
            tp[reg] += h * ad;
        }
    }
#pragma unroll
    for (int msk = 1; msk < 16; msk <<= 1) {
#pragma unroll
        for (int reg = 0; reg < 4; reg++) {
            sp[reg] += __shfl_xor(sp[reg], msk);
            tp[reg] += __shfl_xor(tp[reg], msk);
        }
    }
    if (r == 0) {
#pragma unroll
        for (int reg = 0; reg < 4; reg++) {
            int row = row0 + cg * 4 + reg;
            sbuf[row] = sp[reg];
            tbuf[row] = tp[reg];
        }
    }
}

// ---------------- K2: fused masked-softmax attention @ H ----------------
// grid = 1024 blocks (4/CU), block = 256 thr (4 waves, one per j-quarter).
// Block: 16 i-rows x 128 u of batch b = bid&7. Wave jq owns the 16 rows
// (one A-fragment) x its 512-j quarter (16 tiles of 32).
// Loop: NO barriers, NO LDS. Per iteration k:
//   P(k) from A/t(k) regs -> MFMA ut0-3 (bA) -> reload bA = tile(k+1).ut0-3
//   -> MFMA ut4-7 (bB) -> reload bB = tile(k+1).ut4-7 -> issue A/t(k+2).
// In-order vmcnt: A/t issued LAST -> consuming A/t(k+1)/bA/bB never drains
// a younger A group. 16 waves/CU interleave to cover L2/L3 latency.
__global__ __launch_bounds__(256, 4) void k_attn(const int* __restrict__ A,
                                                 const unsigned short* __restrict__ HT,
                                                 const float* __restrict__ sbuf,
                                                 const float* __restrict__ tbuf,
                                                 float* __restrict__ out) {
    __shared__ float accS[3 * 16 * 132];   // 25.3 KB (combine only)
    __shared__ float dSm[4][16];

    const int tid  = threadIdx.x;
    const int jq   = tid >> 6;          // 0..3 j-quarter (512 j)
    const int lane = tid & 63;
    const int r    = lane & 15;
    const int cg   = lane >> 4;
    const int bid  = blockIdx.x;
    const int b    = bid & 7;           // batch pinned per XCD
    const int it   = bid >> 3;          // 0..127 i-tile
    const int i0   = it * 16;
    const int rot  = it & 15;           // per-block j-tile rotation

    const int irow = i0 + r;
    const float s_r = sbuf[b * 2048 + irow];
    const unsigned short* Hrow = HT + ((size_t)b * 128 + r) * 2048 + jq * 512;
    const int*   Aq = A    + ((size_t)(b * 2048 + irow)) * 2048 + jq * 512 + cg * 8;
    const float* Tq = tbuf + (size_t)b * 2048 + jq * 512 + cg * 8;

    f32x4 acc[8] = {};
    float den = 0.f;

    // ---- register pipeline state ----
    ushort8 bA[4], bB[4];          // B half-tile double buffer
    int4   aP[2][2];               // A depth-2 (slot k&1)
    float4 tP[2][2];

    // ---- prologue: B(0) halves; A/t(0),(1) ----
    {
        const int j0 = rot * 32;
        const int j1 = ((1 + rot) & 15) * 32;
#pragma unroll
        for (int h = 0; h < 4; h++) {
            bA[h] = *(const ushort8*)(Hrow + (size_t)(h * 16) * 2048 + j0 + cg * 8);
            bB[h] = *(const ushort8*)(Hrow + (size_t)((h + 4) * 16) * 2048 + j0 + cg * 8);
        }
        aP[0][0] = *(const int4*)(Aq + j0);
        aP[0][1] = *(const int4*)(Aq + j0 + 4);
        tP[0][0] = *(const float4*)(Tq + j0);
        tP[0][1] = *(const float4*)(Tq + j0 + 4);
        aP[1][0] = *(const int4*)(Aq + j1);
        aP[1][1] = *(const int4*)(Aq + j1 + 4);
        tP[1][0] = *(const float4*)(Tq + j1);
        tP[1][1] = *(const float4*)(Tq + j1 + 4);
    }

#pragma unroll
    for (int k = 0; k < 16; ++k) {
        const int p = k & 1;
        const int jn = ((k + 1 + rot) & 15) * 32 + cg * 8;   // next tile

        // ---- P fragment from A/t(k) regs (forces only groups older than
        //      A/t(k): everything issued after it stays in flight) ----
        float tv[8] = {tP[p][0].x, tP[p][0].y, tP[p][0].z, tP[p][0].w,
                       tP[p][1].x, tP[p][1].y, tP[p][1].z, tP[p][1].w};
        int   ai[8] = {aP[p][0].x, aP[p][0].y, aP[p][0].z, aP[p][0].w,
                       aP[p][1].x, aP[p][1].y, aP[p][1].z, aP[p][1].w};
        bf16x8 pa;
#pragma unroll
        for (int jj = 0; jj < 8; jj++) {
            float x = s_r + tv[jj];
            float e = fmaxf(x, 0.2f * x);          // leaky_relu
            float pp = __expf(e - 16.0f);          // fixed-scale softmax
            pp = ai[jj] > 0 ? pp : 0.f;            // mask
            den += pp;
            pa[jj] = (__bf16)pp;
        }

        // ---- MFMA ut0-3 from bA, then refill bA with tile k+1 ----
#pragma unroll
        for (int h = 0; h < 4; h++) {
            acc[h] = __builtin_amdgcn_mfma_f32_16x16x32_bf16(
                pa, __builtin_bit_cast(bf16x8, bA[h]), acc[h], 0, 0, 0);
        }
        if (k < 15) {
#pragma unroll
            for (int h = 0; h < 4; h++)
                bA[h] = *(const ushort8*)(Hrow + (size_t)(h * 16) * 2048 + jn);
        }
        __builtin_amdgcn_sched_barrier(0);

        // ---- MFMA ut4-7 from bB, then refill bB with tile k+1 ----
#pragma unroll
        for (int h = 0; h < 4; h++) {
            acc[h + 4] = __builtin_amdgcn_mfma_f32_16x16x32_bf16(
                pa, __builtin_bit_cast(bf16x8, bB[h]), acc[h + 4], 0, 0, 0);
        }
        if (k < 15) {
#pragma unroll
            for (int h = 0; h < 4; h++)
                bB[h] = *(const ushort8*)(Hrow + (size_t)((h + 4) * 16) * 2048 + jn);
        }
        __builtin_amdgcn_sched_barrier(0);

        // ---- issue A/t(k+2) LAST (youngest in queue -> never force-drained
        //      by next iteration's B/A consumption) ----
        if (k < 14) {
            const int ja = ((k + 2 + rot) & 15) * 32;
            aP[p][0] = *(const int4*)(Aq + ja);
            aP[p][1] = *(const int4*)(Aq + ja + 4);
            tP[p][0] = *(const float4*)(Tq + ja);
            tP[p][1] = *(const float4*)(Tq + ja + 4);
        }
        __builtin_amdgcn_sched_barrier(0);
    }

    // per-wave denominator per row (sum over the 4 cg k-groups)
    den += __shfl_xor(den, 16);
    den += __shfl_xor(den, 32);

    if (cg == 0) dSm[jq][r] = den;
    if (jq != 0) {
        const int base = (jq - 1) * 16;
#pragma unroll
        for (int ut = 0; ut < 8; ut++)
#pragma unroll
            for (int reg = 0; reg < 4; reg++)
                accS[(base + cg * 4 + reg) * 132 + ut * 16 + r] = acc[ut][reg];
    }
    __syncthreads();
    if (jq == 0) {
        float dinv[4];
#pragma unroll
        for (int reg = 0; reg < 4; reg++) {
            const int row = cg * 4 + reg;
            dinv[reg] = 1.0f / (dSm[0][row] + dSm[1][row] +
                                dSm[2][row] + dSm[3][row]);
        }
#pragma unroll
        for (int ut = 0; ut < 8; ut++) {
#pragma unroll
            for (int reg = 0; reg < 4; reg++) {
                const int lr = cg * 4 + reg;
                float num = acc[ut][reg]
                          + accS[(0 * 16 + lr) * 132 + ut * 16 + r]
                          + accS[(1 * 16 + lr) * 132 + ut * 16 + r]
                          + accS[(2 * 16 + lr) * 132 + ut * 16 + r];
                out[((size_t)(b * 2048 + i0 + lr)) * 128 + ut * 16 + r] =
                    fmaxf(num * dinv[reg], 0.f);
            }
        }
    }
}

extern "C" void kernel_launch(void* const* d_in, const int* in_sizes, int n_in,
                              void* d_out, int out_size, void* d_ws, size_t ws_size,
                              hipStream_t stream) {
    const float* X = (const float*)d_in[0];   // (8,2048,128) f32
    const int*   A = (const int*)d_in[1];     // (8,2048,2048) i32
    const float* W = (const float*)d_in[2];   // (128,128) f32
    const float* a = (const float*)d_in[3];   // (256,1) f32
    float* out = (float*)d_out;               // (8,2048,128) f32

    char* ws = (char*)d_ws;
    float*          sb  = (float*)(ws);                           // 64 KB
    float*          tb  = (float*)(ws + 65536);                   // 64 KB
    unsigned short* HT  = (unsigned short*)(ws + 131072);         // 4 MB

    k_h<<<dim3(256), dim3(256), 0, stream>>>(X, W, a, HT, sb, tb);
    k_attn<<<dim3(1024), dim3(256), 0, stream>>>(A, HT, sb, tb, out);
}

// Round 19
// 59.034 us; speedup vs baseline: 1.6018x; 1.6018x over previous
//
#include <hip/hip_runtime.h>
#include <hip/hip_bf16.h>

// SimpleGATLayer fused kernel set for MI355X (gfx950).
// B=8, N=2048, F=U=128 (hard-coded from reference setup).
//
//  k_h    : W->LDS transpose + H = X@W via MFMA -> HT(b,u,n) bf16, s, t
//  k_attn : fused masked softmax(leaky(s_i+t_j)) @ H, relu, f32 out.
//           Round 19: j-tile 64 on the R16 skeleton — SAME total traffic,
//           HALF the barrier convoys (8 iterations of 2x work instead of
//           16). Tests the per-convoy fixed-tax model (~3400 cy/iter of
//           unexplained stall). LDS 128 KB (4 quarters x dbuf x 16 KB),
//           1 block/CU. A/t depth-2 slots, P before refill (no reg copies).
//           vmcnt ladder 32/20/0 on iteration-group boundaries.

#define NEG_INF -1.0e9f

typedef __bf16 bf16x8 __attribute__((ext_vector_type(8)));
typedef unsigned short ushort8 __attribute__((ext_vector_type(8)));
typedef float f32x4 __attribute__((ext_vector_type(4)));

__device__ __forceinline__ unsigned short f2b(float x) {
    // f32 -> bf16 round-to-nearest-even
    unsigned u = __builtin_bit_cast(unsigned, x);
    u += 0x7fffu + ((u >> 16) & 1u);
    return (unsigned short)(u >> 16);
}

__device__ __forceinline__ void gload_lds16(const void* g, void* l) {
    __builtin_amdgcn_global_load_lds(
        (const __attribute__((address_space(1))) void*)g,
        (__attribute__((address_space(3))) void*)l, 16, 0, 0);
}

// ---------------- K1: H = X@W, plus s,t and HT (W transposed in-kernel) ----
// grid = 256 blocks x 256 thr; each wave computes 16 rows x 128 u.
__global__ __launch_bounds__(256) void k_h(const float* __restrict__ X,
                                           const float* __restrict__ W,
                                           const float* __restrict__ a,
                                           unsigned short* __restrict__ HT,
                                           float* __restrict__ sbuf,
                                           float* __restrict__ tbuf) {
    __shared__ unsigned short WT[128 * 136];   // padded stride: bank spread

    const int tid  = threadIdx.x;
    const int w    = tid >> 6;
    const int lane = tid & 63;
    const int r    = lane & 15;     // MFMA row/col index
    const int cg   = lane >> 4;     // k-group 0..3

    // cooperative W transpose: WT[u][f] = bf16(W[f][u])
    for (int i = tid; i < 16384; i += 256) {
        int u = i >> 7, f = i & 127;
        WT[u * 136 + f] = f2b(W[f * 128 + u]);
    }
    __syncthreads();

    const int row0 = blockIdx.x * 64 + w * 16;  // flattened (b*2048+n) row
    const int b    = row0 >> 11;
    const int n0   = row0 & 2047;
    const int arow = row0 + r;

    f32x4 acc[8] = {};

#pragma unroll
    for (int k0 = 0; k0 < 128; k0 += 32) {
        const float* xp = X + (size_t)arow * 128 + k0 + cg * 8;
        ushort8 xa;
#pragma unroll
        for (int j = 0; j < 8; j++) xa[j] = f2b(xp[j]);
        bf16x8 av = __builtin_bit_cast(bf16x8, xa);
#pragma unroll
        for (int ut = 0; ut < 8; ut++) {
            ushort8 wb = *(const ushort8*)(&WT[(ut * 16 + r) * 136 + k0 + cg * 8]);
            acc[ut] = __builtin_amdgcn_mfma_f32_16x16x32_bf16(
                av, __builtin_bit_cast(bf16x8, wb), acc[ut], 0, 0, 0);
        }
    }

    // D layout: lane holds H[row0 + cg*4 + reg][ut*16 + r]
    float sp[4] = {0.f, 0.f, 0.f, 0.f};
    float tp[4] = {0.f, 0.f, 0.f, 0.f};
#pragma unroll
    for (int ut = 0; ut < 8; ut++) {
        int u = ut * 16 + r;
        float as = a[u];
        float ad = a[128 + u];
#pragma unroll
        for (int reg = 0; reg < 4; reg++) {
            float h = acc[ut][reg];
            int nrow = n0 + cg * 4 + reg;
            HT[((size_t)b * 128 + u) * 2048 + nrow] = f2b(h);
            sp[reg] += h * as;
            tp[reg] += h * ad;
        }
    }
#pragma unroll
    for (int msk = 1; msk < 16; msk <<= 1) {
#pragma unroll
        for (int reg = 0; reg < 4; reg++) {
            sp[reg] += __shfl_xor(sp[reg], msk);
            tp[reg] += __shfl_xor(tp[reg], msk);
        }
    }
    if (r == 0) {
#pragma unroll
        for (int reg = 0; reg < 4; reg++) {
            int row = row0 + cg * 4 + reg;
            sbuf[row] = sp[reg];
            tbuf[row] = tp[reg];
        }
    }
}

// ---------------- K2: fused masked-softmax attention @ H ----------------
// grid = 256 blocks (1/CU), block = 512 thr (8 waves).
// Block: 64 i-rows x 128 u of batch b = bid&7. Wave (jq = w>>1, g = w&1):
// rows [i0+g*32, +32) as two A-fragments (r, r+16), j-quarter jq (512 j,
// 8 tiles of 64). Quarter's staged tile (16 KB, dbuf, hashed chunks) is
// shared by its 2 waves; each wave stages its u-half (8 gload_lds).
// Per tile: 16 ds_read, 32 MFMA, 32 exps — 2x R16's work, half the convoys.
__global__ __launch_bounds__(512, 2) void k_attn(const int* __restrict__ A,
                                                 const unsigned short* __restrict__ HT,
                                                 const float* __restrict__ sbuf,
                                                 const float* __restrict__ tbuf,
                                                 float* __restrict__ out) {
    __shared__ char smem[131072];       // stage: [jq][p][16KB]; combine reuse
    __shared__ float dSm[4][64];

    const int tid  = threadIdx.x;
    const int w    = tid >> 6;          // 0..7
    const int lane = tid & 63;
    const int r    = lane & 15;
    const int cg   = lane >> 4;
    const int jq   = w >> 1;            // j-quarter (512 j)
    const int g    = w & 1;             // row-group (32 rows)
    const int bid  = blockIdx.x;
    const int b    = bid & 7;           // batch pinned per XCD
    const int it   = bid >> 3;          // 0..31 i-tile
    const int i0   = it * 64;
    const int rot  = it & 7;            // per-block j-tile rotation (8 tiles)

    const int irow0 = i0 + g * 32 + r;  // row group rows: irow0, irow0+16
    const float s0 = sbuf[b * 2048 + irow0];
    const float s1 = sbuf[b * 2048 + irow0 + 16];
    const unsigned short* Hb = HT + ((size_t)b * 128) * 2048 + jq * 512;
    const int*   Aq0 = A    + ((size_t)(b * 2048 + irow0)) * 2048 + jq * 512 + cg * 8;
    const int*   Aq1 = Aq0 + 16 * 2048;
    const float* Tq  = tbuf + (size_t)b * 2048 + jq * 512 + cg * 8;

    // staging geometry: tile = 128 u-rows x 128 B (8 chunks of 16 B).
    // Wave stages u-rows [g*64,(g+1)*64): 8 instrs x 8 rows. Chunk hash
    // c_lds = c_global ^ (row&7) (inverse-applied via global src).
    const int srow = (lane >> 3);                     // 0..7 within instr
    const int csrc = (lane & 7) ^ ((lane >> 3) & 7);  // hashed global chunk
    char* const qbase = smem + jq * 32768;            // quarter's 2 buffers
    const unsigned short* src0 = Hb + (size_t)(g * 64 + srow) * 2048 + csrc * 8;
    const int rxor = r & 7;                           // read-side hash

    f32x4 acc0[8] = {};
    f32x4 acc1[8] = {};
    float den0 = 0.f, den1 = 0.f;

    // ---- prologue: stage tile 0; A/t tiles 0,1 into slots ----
    int4   aP0[2][4], aP1[2][4];   // [slot][{h0,h0+4,h1,h1+4}]
    float4 tP[2][4];
    {
        const int j0 = rot * 64;
        const int j1 = ((1 + rot) & 7) * 64;
#pragma unroll
        for (int i = 0; i < 8; i++)
            gload_lds16(src0 + (size_t)i * 8 * 2048 + j0,
                        qbase + g * 8192 + i * 1024);
        aP0[0][0] = *(const int4*)(Aq0 + j0);
        aP0[0][1] = *(const int4*)(Aq0 + j0 + 4);
        aP0[0][2] = *(const int4*)(Aq0 + j0 + 32);
        aP0[0][3] = *(const int4*)(Aq0 + j0 + 36);
        aP1[0][0] = *(const int4*)(Aq1 + j0);
        aP1[0][1] = *(const int4*)(Aq1 + j0 + 4);
        aP1[0][2] = *(const int4*)(Aq1 + j0 + 32);
        aP1[0][3] = *(const int4*)(Aq1 + j0 + 36);
        tP[0][0]  = *(const float4*)(Tq + j0);
        tP[0][1]  = *(const float4*)(Tq + j0 + 4);
        tP[0][2]  = *(const float4*)(Tq + j0 + 32);
        tP[0][3]  = *(const float4*)(Tq + j0 + 36);
        aP0[1][0] = *(const int4*)(Aq0 + j1);
        aP0[1][1] = *(const int4*)(Aq0 + j1 + 4);
        aP0[1][2] = *(const int4*)(Aq0 + j1 + 32);
        aP0[1][3] = *(const int4*)(Aq0 + j1 + 36);
        aP1[1][0] = *(const int4*)(Aq1 + j1);
        aP1[1][1] = *(const int4*)(Aq1 + j1 + 4);
        aP1[1][2] = *(const int4*)(Aq1 + j1 + 32);
        aP1[1][3] = *(const int4*)(Aq1 + j1 + 36);
        tP[1][0]  = *(const float4*)(Tq + j1);
        tP[1][1]  = *(const float4*)(Tq + j1 + 4);
        tP[1][2]  = *(const float4*)(Tq + j1 + 32);
        tP[1][3]  = *(const float4*)(Tq + j1 + 36);
    }
    __syncthreads();   // full drain once: A/t(0,1) + stage0 ready

#pragma unroll
    for (int k = 0; k < 8; ++k) {
        const int p = k & 1;

        // ---- P fragments from slot p (2 row-groups x 2 j-halves) ----
        float tv0[8] = {tP[p][0].x, tP[p][0].y, tP[p][0].z, tP[p][0].w,
                        tP[p][1].x, tP[p][1].y, tP[p][1].z, tP[p][1].w};
        float tv1[8] = {tP[p][2].x, tP[p][2].y, tP[p][2].z, tP[p][2].w,
                        tP[p][3].x, tP[p][3].y, tP[p][3].z, tP[p][3].w};
        int a00[8] = {aP0[p][0].x, aP0[p][0].y, aP0[p][0].z, aP0[p][0].w,
                      aP0[p][1].x, aP0[p][1].y, aP0[p][1].z, aP0[p][1].w};
        int a01[8] = {aP0[p][2].x, aP0[p][2].y, aP0[p][2].z, aP0[p][2].w,
                      aP0[p][3].x, aP0[p][3].y, aP0[p][3].z, aP0[p][3].w};
        int a10[8] = {aP1[p][0].x, aP1[p][0].y, aP1[p][0].z, aP1[p][0].w,
                      aP1[p][1].x, aP1[p][1].y, aP1[p][1].z, aP1[p][1].w};
        int a11[8] = {aP1[p][2].x, aP1[p][2].y, aP1[p][2].z, aP1[p][2].w,
                      aP1[p][3].x, aP1[p][3].y, aP1[p][3].z, aP1[p][3].w};
        bf16x8 pa00, pa01, pa10, pa11;
#pragma unroll
        for (int jj = 0; jj < 8; jj++) {
            float x, e, pp;
            x = s0 + tv0[jj]; e = fmaxf(x, 0.2f * x);
            pp = __expf(e - 16.0f); pp = a00[jj] > 0 ? pp : 0.f;
            den0 += pp; pa00[jj] = (__bf16)pp;
            x = s0 + tv1[jj]; e = fmaxf(x, 0.2f * x);
            pp = __expf(e - 16.0f); pp = a01[jj] > 0 ? pp : 0.f;
            den0 += pp; pa01[jj] = (__bf16)pp;
            x = s1 + tv0[jj]; e = fmaxf(x, 0.2f * x);
            pp = __expf(e - 16.0f); pp = a10[jj] > 0 ? pp : 0.f;
            den1 += pp; pa10[jj] = (__bf16)pp;
            x = s1 + tv1[jj]; e = fmaxf(x, 0.2f * x);
            pp = __expf(e - 16.0f); pp = a11[jj] > 0 ? pp : 0.f;
            den1 += pp; pa11[jj] = (__bf16)pp;
        }

        // ---- issue stage(k+1) into buf p^1 (freed by iter k-1 barrier 2) ----
        if (k < 7) {
            const int jn = ((k + 1 + rot) & 7) * 64;
            char* dst = qbase + (p ^ 1) * 16384 + g * 8192;
#pragma unroll
            for (int i = 0; i < 8; i++)
                gload_lds16(src0 + (size_t)i * 8 * 2048 + jn,
                            dst + i * 1024);
        }
        __builtin_amdgcn_sched_barrier(0);   // pin: stage before A refill
        // ---- refill A/t(k+2) into slot p (P already consumed it) ----
        if (k < 6) {
            const int ja = ((k + 2 + rot) & 7) * 64;
            aP0[p][0] = *(const int4*)(Aq0 + ja);
            aP0[p][1] = *(const int4*)(Aq0 + ja + 4);
            aP0[p][2] = *(const int4*)(Aq0 + ja + 32);
            aP0[p][3] = *(const int4*)(Aq0 + ja + 36);
            aP1[p][0] = *(const int4*)(Aq1 + ja);
            aP1[p][1] = *(const int4*)(Aq1 + ja + 4);
            aP1[p][2] = *(const int4*)(Aq1 + ja + 32);
            aP1[p][3] = *(const int4*)(Aq1 + ja + 36);
            tP[p][0]  = *(const float4*)(Tq + ja);
            tP[p][1]  = *(const float4*)(Tq + ja + 4);
            tP[p][2]  = *(const float4*)(Tq + ja + 32);
            tP[p][3]  = *(const float4*)(Tq + ja + 36);
        }

        // ---- counted wait on iteration-group boundary:
        // steady outstanding = A/t(k+1)[12] + S(k+1)[8] + A/t(k+2)[12] = 32.
        if (k < 6)       asm volatile("s_waitcnt vmcnt(32)" ::: "memory");
        else if (k == 6) asm volatile("s_waitcnt vmcnt(20)" ::: "memory");
        else             asm volatile("s_waitcnt vmcnt(0)"  ::: "memory");
        __builtin_amdgcn_s_barrier();
        __builtin_amdgcn_sched_barrier(0);   // no ds_read hoisting (rule #18)

        // ---- B fragments from staged tile: 16 ds_read, 32 MFMA ----
        const char* buf = qbase + p * 16384;
#pragma unroll
        for (int ut = 0; ut < 8; ut++) {
            const int base = (ut * 16 + r) * 128;
            ushort8 h0 = *(const ushort8*)(buf + base + ((cg ^ rxor) * 16));
            ushort8 h1 = *(const ushort8*)(buf + base + (((4 + cg) ^ rxor) * 16));
            bf16x8 hb0 = __builtin_bit_cast(bf16x8, h0);
            bf16x8 hb1 = __builtin_bit_cast(bf16x8, h1);
            acc0[ut] = __builtin_amdgcn_mfma_f32_16x16x32_bf16(pa00, hb0, acc0[ut], 0, 0, 0);
            acc0[ut] = __builtin_amdgcn_mfma_f32_16x16x32_bf16(pa01, hb1, acc0[ut], 0, 0, 0);
            acc1[ut] = __builtin_amdgcn_mfma_f32_16x16x32_bf16(pa10, hb0, acc1[ut], 0, 0, 0);
            acc1[ut] = __builtin_amdgcn_mfma_f32_16x16x32_bf16(pa11, hb1, acc1[ut], 0, 0, 0);
        }

        if (k < 7) {
            __builtin_amdgcn_s_barrier();        // WAR guard: buf p is staged
            __builtin_amdgcn_sched_barrier(0);   // into next iteration
        }
    }

    // per-wave denominators per row (sum over the 4 cg k-groups)
    den0 += __shfl_xor(den0, 16);
    den0 += __shfl_xor(den0, 32);
    den1 += __shfl_xor(den1, 16);
    den1 += __shfl_xor(den1, 32);

    __syncthreads();   // everyone done with stage buffers before accS reuse

    if (cg == 0) { dSm[jq][g * 32 + r] = den0; dSm[jq][g * 32 + 16 + r] = den1; }

    // ---- combine the 4 j-quarters in two row-group passes (smem reuse) ----
    float* accS = (float*)smem;
#pragma unroll
    for (int gg = 0; gg < 2; ++gg) {
        __syncthreads();
        if (g == gg && jq != 0) {
            const int base = (jq - 1) * 32;
#pragma unroll
            for (int ut = 0; ut < 8; ut++)
#pragma unroll
                for (int reg = 0; reg < 4; reg++) {
                    accS[(base + cg * 4 + reg) * 132 + ut * 16 + r]      = acc0[ut][reg];
                    accS[(base + 16 + cg * 4 + reg) * 132 + ut * 16 + r] = acc1[ut][reg];
                }
        }
        __syncthreads();
        if (g == gg && jq == 0) {
            float dinv0[4], dinv1[4];
#pragma unroll
            for (int reg = 0; reg < 4; reg++) {
                const int row0_ = gg * 32 + cg * 4 + reg;
                const int row1_ = gg * 32 + 16 + cg * 4 + reg;
                dinv0[reg] = 1.0f / (dSm[0][row0_] + dSm[1][row0_] +
                                     dSm[2][row0_] + dSm[3][row0_]);
                dinv1[reg] = 1.0f / (dSm[0][row1_] + dSm[1][row1_] +
                                     dSm[2][row1_] + dSm[3][row1_]);
            }
#pragma unroll
            for (int ut = 0; ut < 8; ut++) {
#pragma unroll
                for (int reg = 0; reg < 4; reg++) {
                    const int lr0 = cg * 4 + reg;        // within group
                    const int lr1 = 16 + cg * 4 + reg;
                    float n0 = acc0[ut][reg]
                             + accS[(0 * 32 + lr0) * 132 + ut * 16 + r]
                             + accS[(1 * 32 + lr0) * 132 + ut * 16 + r]
                             + accS[(2 * 32 + lr0) * 132 + ut * 16 + r];
                    float n1 = acc1[ut][reg]
                             + accS[(0 * 32 + lr1) * 132 + ut * 16 + r]
                             + accS[(1 * 32 + lr1) * 132 + ut * 16 + r]
                             + accS[(2 * 32 + lr1) * 132 + ut * 16 + r];
                    out[((size_t)(b * 2048 + i0 + gg * 32 + lr0)) * 128 +
                        ut * 16 + r] = fmaxf(n0 * dinv0[reg], 0.f);
                    out[((size_t)(b * 2048 + i0 + gg * 32 + lr1)) * 128 +
                        ut * 16 + r] = fmaxf(n1 * dinv1[reg], 0.f);
                }
            }
        }
    }
}

extern "C" void kernel_launch(void* const* d_in, const int* in_sizes, int n_in,
                              void* d_out, int out_size, void* d_ws, size_t ws_size,
                              hipStream_t stream) {
    const float* X = (const float*)d_in[0];   // (8,2048,128) f32
    const int*   A = (const int*)d_in[1];     // (8,2048,2048) i32
    const float* W = (const float*)d_in[2];   // (128,128) f32
    const float* a = (const float*)d_in[3];   // (256,1) f32
    float* out = (float*)d_out;               // (8,2048,128) f32

    char* ws = (char*)d_ws;
    float*          sb  = (float*)(ws);                           // 64 KB
    float*          tb  = (float*)(ws + 65536);                   // 64 KB
    unsigned short* HT  = (unsigned short*)(ws + 131072);         // 4 MB

    k_h<<<dim3(256), dim3(256), 0, stream>>>(X, W, a, HT, sb, tb);
    k_attn<<<dim3(256), dim3(512), 0, stream>>>(A, HT, sb, tb, out);
}